// Round 2
// baseline (552.956 us; speedup 1.0000x reference)
//
#include <hip/hip_runtime.h>
#include <math.h>

#define NUM_CLASSES 81

// ---------------- Phase 1: per-row softmax stats + box decode -> workspace ----
// One wave per row. Writes 24 B/row: float4 decoded+clipped box, float2 (max, 1/sum).
__global__ __launch_bounds__(256) void stats_kernel(
    const float* __restrict__ logits,
    const float* __restrict__ box_reg,
    const float* __restrict__ prop,
    const int* __restrict__ img_w_p,
    const int* __restrict__ img_h_p,
    float4* __restrict__ ws_box,
    float2* __restrict__ ws_ms,
    int N)
{
    const int wave = threadIdx.x >> 6;
    const int lane = threadIdx.x & 63;
    const int row  = blockIdx.x * 4 + wave;
    if (row >= N) return;

    // ---- softmax stats over C=81 within one wave ----
    const float* lrow = logits + (size_t)row * NUM_CLASSES;
    const bool has2 = (lane < NUM_CLASSES - 64);  // lanes 0..16 hold a 2nd elem
    float v0 = lrow[lane];
    float v1 = has2 ? lrow[64 + lane] : -INFINITY;

    float m = fmaxf(v0, v1);
    #pragma unroll
    for (int off = 32; off > 0; off >>= 1)
        m = fmaxf(m, __shfl_xor(m, off));

    float s = expf(v0 - m) + (has2 ? expf(v1 - m) : 0.0f);
    #pragma unroll
    for (int off = 32; off > 0; off >>= 1)
        s += __shfl_xor(s, off);

    if (lane == 0) {
        // ---- decode box (single lane; short divergent tail) ----
        const float wmax = (float)(*img_w_p) - 1.0f;
        const float hmax = (float)(*img_h_p) - 1.0f;
        const float b0 = prop[row * 4 + 0];
        const float b1 = prop[row * 4 + 1];
        const float b2 = prop[row * 4 + 2];
        const float b3 = prop[row * 4 + 3];
        const float r0 = box_reg[row * 4 + 0];
        const float r1 = box_reg[row * 4 + 1];
        const float r2 = box_reg[row * 4 + 2];
        const float r3 = box_reg[row * 4 + 3];

        const float BBOX_XFORM_CLIP = 4.135166556742356f; // log(1000/16)
        const float w  = b2 - b0 + 1.0f;
        const float h  = b3 - b1 + 1.0f;
        const float cx = b0 + 0.5f * w;
        const float cy = b1 + 0.5f * h;
        const float dx = r0 * 0.1f;
        const float dy = r1 * 0.1f;
        const float dw = fminf(r2 * 0.2f, BBOX_XFORM_CLIP);
        const float dh = fminf(r3 * 0.2f, BBOX_XFORM_CLIP);
        const float px = dx * w + cx;
        const float py = dy * h + cy;
        const float pw = expf(dw) * w;
        const float ph = expf(dh) * h;
        const float x1 = fminf(fmaxf(px - 0.5f * pw, 0.0f), wmax);
        const float y1 = fminf(fmaxf(py - 0.5f * ph, 0.0f), hmax);
        const float x2 = fminf(fmaxf(px + 0.5f * pw - 1.0f, 0.0f), wmax);
        const float y2 = fminf(fmaxf(py + 0.5f * ph - 1.0f, 0.0f), hmax);

        ws_box[row] = make_float4(x1, y1, x2, y2);
        ws_ms[row]  = make_float2(m, 1.0f / s);
    }
}

// ---------------- Phase 2: pure streaming elementwise writer --------------
// One thread per (row, class). 4 B logit read + 24 B broadcast ws read (cached),
// 20 B coalesced write.
__global__ __launch_bounds__(256) void write_kernel(
    const float* __restrict__ logits,
    const float4* __restrict__ ws_box,
    const float2* __restrict__ ws_ms,
    float4* __restrict__ out_boxes,
    float* __restrict__ out_scores,
    int total)
{
    const int j = blockIdx.x * blockDim.x + threadIdx.x;
    if (j >= total) return;
    const unsigned row = (unsigned)j / (unsigned)NUM_CLASSES;  // magic-mul
    const float4 box = ws_box[row];
    const float2 ms  = ws_ms[row];
    const float  sc  = __expf(logits[j] - ms.x) * ms.y;
    out_boxes[j]  = box;
    out_scores[j] = sc;
}

extern "C" void kernel_launch(void* const* d_in, const int* in_sizes, int n_in,
                              void* d_out, int out_size, void* d_ws, size_t ws_size,
                              hipStream_t stream) {
    const float* logits  = (const float*)d_in[0];
    const float* box_reg = (const float*)d_in[1];
    const float* prop    = (const float*)d_in[2];
    const int*   img_w_p = (const int*)d_in[3];
    const int*   img_h_p = (const int*)d_in[4];

    const int N = in_sizes[1] / 4;       // box_regression is (N,4)
    const int total = N * NUM_CLASSES;   // 21,233,664

    float* out_boxes  = (float*)d_out;
    float* out_scores = out_boxes + (size_t)N * NUM_CLASSES * 4;

    // workspace layout: [ float4 box ][ float2 (max, 1/sum) ]
    float4* ws_box = (float4*)d_ws;
    float2* ws_ms  = (float2*)((char*)d_ws + (size_t)N * sizeof(float4));

    const int blocks1 = (N + 3) / 4;  // 4 waves (rows) per 256-thread block
    stats_kernel<<<blocks1, 256, 0, stream>>>(
        logits, box_reg, prop, img_w_p, img_h_p, ws_box, ws_ms, N);

    const int blocks2 = (total + 255) / 256;
    write_kernel<<<blocks2, 256, 0, stream>>>(
        logits, ws_box, ws_ms, (float4*)out_boxes, out_scores, total);
}

// Round 3
// 492.228 us; speedup vs baseline: 1.1234x; 1.1234x over previous
//
#include <hip/hip_runtime.h>
#include <math.h>

#define NUM_CLASSES 81
#define ROWS_PER_BLOCK 16
#define ELEMS_PER_BLOCK (ROWS_PER_BLOCK * NUM_CLASSES)  // 1296

// One 256-thread block handles 16 rows.
//   Phase A: coalesced load of 16x81 logits -> LDS; threads 0..15 decode boxes.
//   Phase B: softmax, 16 lanes per row (4 rows per wave), 4 shuffle rounds.
//   Phase C: fully-coalesced contiguous writes of 1296 float4 boxes + 1296 scores.
__global__ __launch_bounds__(256) void fused_kernel(
    const float* __restrict__ logits,
    const float4* __restrict__ box_reg4,
    const float4* __restrict__ prop4,
    const int* __restrict__ img_w_p,
    const int* __restrict__ img_h_p,
    float4* __restrict__ out_boxes4,   // out_boxes viewed as N*81 float4s
    float* __restrict__ out_scores,
    int N)
{
    __shared__ float  lds_val[ELEMS_PER_BLOCK];  // logits, then scores (in place)
    __shared__ float4 lds_box[ROWS_PER_BLOCK];

    const int tid = threadIdx.x;
    const int block_row0 = blockIdx.x * ROWS_PER_BLOCK;
    if (block_row0 >= N) return;
    const int rows  = min(ROWS_PER_BLOCK, N - block_row0);
    const int elems = rows * NUM_CLASSES;

    // ---------- Phase A: stage logits, decode boxes ----------
    const float* lbase = logits + (size_t)block_row0 * NUM_CLASSES;
    #pragma unroll
    for (int i = 0; i < 6; ++i) {
        int e = tid + i * 256;
        if (e < elems) lds_val[e] = lbase[e];
    }

    if (tid < rows) {
        const int row = block_row0 + tid;
        const float4 b = prop4[row];      // coalesced 256B across 16 threads
        const float4 r = box_reg4[row];
        const float wmax = (float)(*img_w_p) - 1.0f;
        const float hmax = (float)(*img_h_p) - 1.0f;

        const float BBOX_XFORM_CLIP = 4.135166556742356f; // log(1000/16)
        const float w  = b.z - b.x + 1.0f;
        const float h  = b.w - b.y + 1.0f;
        const float cx = b.x + 0.5f * w;
        const float cy = b.y + 0.5f * h;
        const float dx = r.x * 0.1f;
        const float dy = r.y * 0.1f;
        const float dw = fminf(r.z * 0.2f, BBOX_XFORM_CLIP);
        const float dh = fminf(r.w * 0.2f, BBOX_XFORM_CLIP);
        const float px = dx * w + cx;
        const float py = dy * h + cy;
        const float pw = expf(dw) * w;
        const float ph = expf(dh) * h;
        const float x1 = fminf(fmaxf(px - 0.5f * pw, 0.0f), wmax);
        const float y1 = fminf(fmaxf(py - 0.5f * ph, 0.0f), hmax);
        const float x2 = fminf(fmaxf(px + 0.5f * pw - 1.0f, 0.0f), wmax);
        const float y2 = fminf(fmaxf(py + 0.5f * ph - 1.0f, 0.0f), hmax);
        lds_box[tid] = make_float4(x1, y1, x2, y2);
    }
    __syncthreads();

    // ---------- Phase B: softmax, 16 lanes per row ----------
    const int sub = tid & 15;        // lane within the row's 16-lane group
    const int rl  = tid >> 4;        // local row 0..15
    if (rl < rows) {
        float* rowv = lds_val + rl * NUM_CLASSES;

        float v[6];
        float m = -INFINITY;
        #pragma unroll
        for (int i = 0; i < 6; ++i) {
            const int k = sub + i * 16;
            if (k < NUM_CLASSES) { v[i] = rowv[k]; m = fmaxf(m, v[i]); }
            else                 { v[i] = -INFINITY; }
        }
        #pragma unroll
        for (int off = 1; off <= 8; off <<= 1)
            m = fmaxf(m, __shfl_xor(m, off));

        float s = 0.0f;
        #pragma unroll
        for (int i = 0; i < 6; ++i) {
            const int k = sub + i * 16;
            if (k < NUM_CLASSES) { v[i] = __expf(v[i] - m); s += v[i]; }
        }
        #pragma unroll
        for (int off = 1; off <= 8; off <<= 1)
            s += __shfl_xor(s, off);

        const float inv = 1.0f / s;
        #pragma unroll
        for (int i = 0; i < 6; ++i) {
            const int k = sub + i * 16;
            if (k < NUM_CLASSES) rowv[k] = v[i] * inv;  // own slots only: no race
        }
    }
    __syncthreads();

    // ---------- Phase C: coalesced contiguous output writes ----------
    const size_t sbase = (size_t)block_row0 * NUM_CLASSES;

    // scores: contiguous [sbase, sbase+elems)
    float* sdst = out_scores + sbase;
    #pragma unroll
    for (int i = 0; i < 6; ++i) {
        int e = tid + i * 256;
        if (e < elems) sdst[e] = lds_val[e];
    }

    // boxes: contiguous float4s [sbase, sbase+elems); row = j/81 via u24 magic
    float4* bdst = out_boxes4 + sbase;
    #pragma unroll
    for (int i = 0; i < 6; ++i) {
        int j = tid + i * 256;
        if (j < elems) {
            const int r = (int)(((unsigned)j * 12946u) >> 20);  // j/81, u24 mul
            bdst[j] = lds_box[r];
        }
    }
}

extern "C" void kernel_launch(void* const* d_in, const int* in_sizes, int n_in,
                              void* d_out, int out_size, void* d_ws, size_t ws_size,
                              hipStream_t stream) {
    const float* logits   = (const float*)d_in[0];
    const float4* boxreg4 = (const float4*)d_in[1];
    const float4* prop4   = (const float4*)d_in[2];
    const int*   img_w_p  = (const int*)d_in[3];
    const int*   img_h_p  = (const int*)d_in[4];

    const int N = in_sizes[1] / 4;  // box_regression is (N,4)

    float4* out_boxes4 = (float4*)d_out;
    float*  out_scores = (float*)d_out + (size_t)N * NUM_CLASSES * 4;

    const int blocks = (N + ROWS_PER_BLOCK - 1) / ROWS_PER_BLOCK;
    fused_kernel<<<blocks, 256, 0, stream>>>(
        logits, boxreg4, prop4, img_w_p, img_h_p, out_boxes4, out_scores, N);
}

// Round 4
// 487.944 us; speedup vs baseline: 1.1332x; 1.0088x over previous
//
#include <hip/hip_runtime.h>
#include <math.h>

#define NUM_CLASSES 81
#define ROWS_PER_BLOCK 16
#define ELEMS_PER_BLOCK (ROWS_PER_BLOCK * NUM_CLASSES)   // 1296 floats
#define VEC_PER_BLOCK   (ELEMS_PER_BLOCK / 4)            // 324 float4s

typedef float vfloat4 __attribute__((ext_vector_type(4)));

// One 256-thread block = 16 rows.
//   Phase A: float4-coalesced load of 16x81 logits -> LDS; threads 0..15 decode boxes.
//   Phase B: softmax, 16 lanes per row (4 rows per wave), 4 shuffle rounds.
//   Phase C: nontemporal float4 writes: 1296 box float4s + 324 score float4s.
__global__ __launch_bounds__(256) void fused_kernel(
    const float* __restrict__ logits,
    const float4* __restrict__ box_reg4,
    const float4* __restrict__ prop4,
    const int* __restrict__ img_w_p,
    const int* __restrict__ img_h_p,
    float* __restrict__ out_boxes,
    float* __restrict__ out_scores,
    int N)
{
    __shared__ vfloat4 lds4[VEC_PER_BLOCK];          // logits, then scores (in place)
    float* lds_val = (float*)lds4;
    __shared__ float4 lds_box[ROWS_PER_BLOCK];

    const int tid = threadIdx.x;
    const int block_row0 = blockIdx.x * ROWS_PER_BLOCK;
    if (block_row0 >= N) return;
    const int rows  = min(ROWS_PER_BLOCK, N - block_row0);
    const bool full = (rows == ROWS_PER_BLOCK);
    const int elems = rows * NUM_CLASSES;

    // ---------- Phase A: stage logits (float4), decode boxes ----------
    const float* lbase = logits + (size_t)block_row0 * NUM_CLASSES;
    if (full) {
        const vfloat4* lbase4 = (const vfloat4*)lbase;   // 16B-aligned: row0*324B, row0%16==0
        { int idx = tid;        if (true)               lds4[idx] = lbase4[idx]; }
        { int idx = tid + 256;  if (idx < VEC_PER_BLOCK) lds4[idx] = lbase4[idx]; }
    } else {
        for (int i = 0; i < 6; ++i) {
            int e = tid + i * 256;
            if (e < elems) lds_val[e] = lbase[e];
        }
    }

    if (tid < rows) {
        const int row = block_row0 + tid;
        const float4 b = prop4[row];
        const float4 r = box_reg4[row];
        const float wmax = (float)(*img_w_p) - 1.0f;
        const float hmax = (float)(*img_h_p) - 1.0f;

        const float BBOX_XFORM_CLIP = 4.135166556742356f; // log(1000/16)
        const float w  = b.z - b.x + 1.0f;
        const float h  = b.w - b.y + 1.0f;
        const float cx = b.x + 0.5f * w;
        const float cy = b.y + 0.5f * h;
        const float dx = r.x * 0.1f;
        const float dy = r.y * 0.1f;
        const float dw = fminf(r.z * 0.2f, BBOX_XFORM_CLIP);
        const float dh = fminf(r.w * 0.2f, BBOX_XFORM_CLIP);
        const float px = dx * w + cx;
        const float py = dy * h + cy;
        const float pw = expf(dw) * w;
        const float ph = expf(dh) * h;
        const float x1 = fminf(fmaxf(px - 0.5f * pw, 0.0f), wmax);
        const float y1 = fminf(fmaxf(py - 0.5f * ph, 0.0f), hmax);
        const float x2 = fminf(fmaxf(px + 0.5f * pw - 1.0f, 0.0f), wmax);
        const float y2 = fminf(fmaxf(py + 0.5f * ph - 1.0f, 0.0f), hmax);
        lds_box[tid] = make_float4(x1, y1, x2, y2);
    }
    __syncthreads();

    // ---------- Phase B: softmax, 16 lanes per row ----------
    const int sub = tid & 15;        // lane within the row's 16-lane group
    const int rl  = tid >> 4;        // local row 0..15
    if (rl < rows) {
        float* rowv = lds_val + rl * NUM_CLASSES;

        float v[6];
        float m = -INFINITY;
        #pragma unroll
        for (int i = 0; i < 6; ++i) {
            const int k = sub + i * 16;
            if (k < NUM_CLASSES) { v[i] = rowv[k]; m = fmaxf(m, v[i]); }
            else                 { v[i] = -INFINITY; }
        }
        #pragma unroll
        for (int off = 1; off <= 8; off <<= 1)
            m = fmaxf(m, __shfl_xor(m, off));

        float s = 0.0f;
        #pragma unroll
        for (int i = 0; i < 6; ++i) {
            const int k = sub + i * 16;
            if (k < NUM_CLASSES) { v[i] = __expf(v[i] - m); s += v[i]; }
        }
        #pragma unroll
        for (int off = 1; off <= 8; off <<= 1)
            s += __shfl_xor(s, off);

        const float inv = 1.0f / s;
        #pragma unroll
        for (int i = 0; i < 6; ++i) {
            const int k = sub + i * 16;
            if (k < NUM_CLASSES) rowv[k] = v[i] * inv;  // own slots only: no race
        }
    }
    __syncthreads();

    // ---------- Phase C: nontemporal coalesced output writes ----------
    const size_t sbase = (size_t)block_row0 * NUM_CLASSES;

    if (full) {
        // scores: 324 float4s, contiguous, nontemporal
        vfloat4* sdst4 = (vfloat4*)(out_scores + sbase);
        { int idx = tid;       __builtin_nontemporal_store(lds4[idx], sdst4 + idx); }
        { int idx = tid + 256; if (idx < VEC_PER_BLOCK)
                               __builtin_nontemporal_store(lds4[idx], sdst4 + idx); }

        // boxes: 1296 float4s, contiguous; row = j/81 via u24 magic-mul
        vfloat4* bdst4 = (vfloat4*)(out_boxes + sbase * 4);
        #pragma unroll
        for (int i = 0; i < 6; ++i) {
            const int j = tid + i * 256;
            if (i < 5 || j < ELEMS_PER_BLOCK) {
                const int r = (int)(((unsigned)j * 12946u) >> 20);  // j/81
                const float4 bx = lds_box[r];
                vfloat4 bv = { bx.x, bx.y, bx.z, bx.w };
                __builtin_nontemporal_store(bv, bdst4 + j);
            }
        }
    } else {
        float* sdst = out_scores + sbase;
        for (int i = 0; i < 6; ++i) {
            int e = tid + i * 256;
            if (e < elems) sdst[e] = lds_val[e];
        }
        float4* bdst = (float4*)(out_boxes + sbase * 4);
        for (int i = 0; i < 6; ++i) {
            int j = tid + i * 256;
            if (j < elems) {
                const int r = (int)(((unsigned)j * 12946u) >> 20);
                bdst[j] = lds_box[r];
            }
        }
    }
}

extern "C" void kernel_launch(void* const* d_in, const int* in_sizes, int n_in,
                              void* d_out, int out_size, void* d_ws, size_t ws_size,
                              hipStream_t stream) {
    const float* logits   = (const float*)d_in[0];
    const float4* boxreg4 = (const float4*)d_in[1];
    const float4* prop4   = (const float4*)d_in[2];
    const int*   img_w_p  = (const int*)d_in[3];
    const int*   img_h_p  = (const int*)d_in[4];

    const int N = in_sizes[1] / 4;  // box_regression is (N,4)

    float* out_boxes  = (float*)d_out;
    float* out_scores = out_boxes + (size_t)N * NUM_CLASSES * 4;

    const int blocks = (N + ROWS_PER_BLOCK - 1) / ROWS_PER_BLOCK;
    fused_kernel<<<blocks, 256, 0, stream>>>(
        logits, boxreg4, prop4, img_w_p, img_h_p, out_boxes, out_scores, N);
}